// Round 2
// baseline (21507.655 us; speedup 1.0000x reference)
//
#include <hip/hip_runtime.h>
#include <hip/hip_bf16.h>

// ---------------------------------------------------------------------------
// 3-layer original-paper GRU, B=128, T=128, I=512, H={512,1024,2048}.
// Round 7: uniform 256KB-per-block tiling via (128,128) tiles + split-K.
//  - Calibration from R6: per-CU global->LDS streaming ~11 B/cy; critical
//    path = max bytes staged per CU. R6 critical block staged 768KB.
//  - Now EVERY block stages exactly 4 chunks x 64KB = 256KB:
//      L2 gemms (K=2048): split-K G=4; K=1024 gemms: G=2; gi1 (K=512): G=1.
//  - Split-K reduction: partial f32 [128x128] per block -> threadfence ->
//    atomic arrive -> spin until G arrivals (all blocks co-resident:
//    grid<=256, 128KB LDS => 1 block/CU) -> each block epilogues its own
//    disjoint 128/G-column share. Counters zeroed by the other kernel.
//  - Same diagonal schedule as R6 (layer l at t = u-2l, gi decoupled).
// Workspace ~117 MB.
// ---------------------------------------------------------------------------

typedef __attribute__((ext_vector_type(8))) short s16x8;
typedef __attribute__((ext_vector_type(4))) float f32x4;

#define LLDS16(g, s)                                                          \
  __builtin_amdgcn_global_load_lds(                                           \
      (const __attribute__((address_space(1))) void*)(g),                     \
      (__attribute__((address_space(3))) void*)(s), 16, 0, 0)

__device__ __forceinline__ unsigned short f2b(float f) {
  unsigned int u = __float_as_uint(f);
  unsigned int r = (u + 0x7FFFu + ((u >> 16) & 1u)) >> 16;
  return (unsigned short)r;
}
__device__ __forceinline__ float sigmoidf_(float x) {
  return 1.0f / (1.0f + __expf(-x));
}
__device__ __forceinline__ float tanhf_(float x) {
  x = fminf(fmaxf(x, -15.0f), 15.0f);
  float e = __expf(-2.0f * x);
  return (1.0f - e) / (1.0f + e);
}

struct DiagP {
  const unsigned short* xb;            // [B,T,I] bf16
  const unsigned short* wihzr0;        // [2*512, 512]
  const unsigned short* wihn0;         // [512, 512]
  const unsigned short* wihF[3];       // full [3H, inl] (l=1,2 used)
  const unsigned short* whhzr[3];      // [2H, H]
  const unsigned short* whhn[3];       // [H, H]
  const float* bias[3];                // [3H]
  float* hf[3][2];                     // f32 h, 2 slots (tick parity)
  unsigned short* hb[3][2];            // bf16 h, 2 slots
  float* zb[3];                        // [B,H] f32
  unsigned short* rh[3];               // [B,H] bf16
  float* gi[3][2];                     // [B,3H] f32, 2 slots (t parity)
  const float* mask;                   // [B,T]
  float* out;                          // [B,3584]
  float* pzr;                          // partials zr: 56 grp x 4 x 16384 f32
  float* pn;                           // partials n : 76 grp x 4 x 16384 f32
  int* czr;                            // 128 counters
  int* cn;                             // 128 counters
};

// ---- stage a 128x128 bf16 tile (32KB), XOR-swizzled via global source ----
// LDS layout linear: row r at r*256B; reader applies cg ^= (r&15).
__device__ __forceinline__ void stage128(const unsigned short* __restrict__ g,
                                         size_t ld, int rowbase, int k0,
                                         unsigned short* lds) {
  const int tid = threadIdx.x;
  const int wave = tid >> 6, lane = tid & 63;
#pragma unroll
  for (int j = 0; j < 4; ++j) {
    int s = wave * 4 + j;             // 0..31, 1KB segments (4 rows each)
    int r = s * 4 + (lane >> 4);      // 0..127
    int cg = (lane & 15) ^ (r & 15);
    LLDS16(g + (size_t)(rowbase + r) * ld + k0 + cg * 8, lds + s * 512);
  }
}

// ---- one BK=128 chunk on a 128x128 tile: 8 waves as (wr=wave>>2) x
// (wc=wave&3); each wave 4x2 16x16x32 frags: 6 ds_read_b128 per 8 MFMA.
__device__ __forceinline__ void cchunk128(const unsigned short* Ab,
                                          const unsigned short* Bb,
                                          f32x4 acc[4][2]) {
  const int tid = threadIdx.x;
  const int wave = tid >> 6, lane = tid & 63;
  const int wr = wave >> 2, wc = wave & 3, quad = lane >> 4, l16 = lane & 15;
#pragma unroll
  for (int ks = 0; ks < 4; ++ks) {
    int kg = ks * 4 + quad;
    s16x8 bv[2], av[4];
#pragma unroll
    for (int ni = 0; ni < 2; ++ni) {
      int br = wc * 32 + ni * 16 + l16;
      bv[ni] =
          *(const s16x8*)(Bb + (size_t)br * 128 + ((kg ^ (br & 15)) * 8));
    }
#pragma unroll
    for (int mi = 0; mi < 4; ++mi) {
      int r = wr * 64 + mi * 16 + l16;
      av[mi] = *(const s16x8*)(Ab + (size_t)r * 128 + ((kg ^ (r & 15)) * 8));
    }
#pragma unroll
    for (int mi = 0; mi < 4; ++mi)
#pragma unroll
      for (int ni = 0; ni < 2; ++ni)
        acc[mi][ni] = __builtin_amdgcn_mfma_f32_16x16x32_bf16(
            av[mi], bv[ni], acc[mi][ni], 0, 0, 0);
  }
}

// ---- 4-chunk (K=512) GEMM slice: acc += A[:,k0:k0+512] @ B[rows,k0:+512]^T
__device__ __forceinline__ void gemm_run(const unsigned short* __restrict__ A,
                                         size_t ldA,
                                         const unsigned short* __restrict__ B,
                                         size_t ldB, int browbase, int k0,
                                         unsigned short* As, unsigned short* Bs,
                                         f32x4 acc[4][2]) {
  auto issue = [&](int c, int buf) {
    stage128(A, ldA, 0, k0 + c * 128, As + buf * 16384);
    stage128(B, ldB, browbase, k0 + c * 128, Bs + buf * 16384);
  };
  issue(0, 0);
#pragma unroll 1
  for (int c = 0; c < 4; ++c) {
    __syncthreads();  // drains vmcnt: chunk c resident; WAR-protects buffers
    if (c + 1 < 4) issue(c + 1, (c + 1) & 1);
    cchunk128(As + (c & 1) * 16384, Bs + (c & 1) * 16384, acc);
  }
}

__device__ __forceinline__ void store_partial(float* __restrict__ pb,
                                              f32x4 acc[4][2]) {
  const int tid = threadIdx.x;
  const int wave = tid >> 6, lane = tid & 63;
  const int wr = wave >> 2, wc = wave & 3, quad = lane >> 4, l16 = lane & 15;
#pragma unroll
  for (int mi = 0; mi < 4; ++mi)
#pragma unroll
    for (int ni = 0; ni < 2; ++ni)
#pragma unroll
      for (int rr = 0; rr < 4; ++rr) {
        int row = wr * 64 + mi * 16 + quad * 4 + rr;
        int col = wc * 32 + ni * 16 + l16;
        pb[row * 128 + col] = acc[mi][ni][rr];
      }
}

// all-arrive spin barrier across the G co-resident blocks of one tile group
__device__ __forceinline__ void arrive_wait(int* cnt, int G) {
  __threadfence();      // flush each thread's partial stores device-wide
  __syncthreads();
  if (threadIdx.x == 0) {
    atomicAdd(cnt, 1);  // device-scope by default
    while (__hip_atomic_load(cnt, __ATOMIC_ACQUIRE,
                             __HIP_MEMORY_SCOPE_AGENT) < G)
      __builtin_amdgcn_s_sleep(2);
  }
  __syncthreads();
}

// ---- zr: hidden/x zr-gate GEMMs for tick u. 176 blocks, all 4 chunks. ----
__global__ __launch_bounds__(512) void diag_zr(DiagP p, int u) {
  __shared__ unsigned short As[2 * 16384], Bs[2 * 16384];
  const int blk = blockIdx.x, tid = threadIdx.x;
  if (blk == 0 && tid < 128) p.cn[tid] = 0;  // reset counters for n launch
  int l, tile, kb, G;
  if (blk < 16) {
    l = 0; tile = blk >> 1; kb = blk & 1; G = 2;
  } else if (blk < 48) {
    l = 1; tile = (blk - 16) >> 1; kb = (blk - 16) & 1; G = 2;
  } else {
    l = 2; tile = (blk - 48) >> 2; kb = (blk - 48) & 3; G = 4;
  }
  const int t = u - 2 * l;
  if (t < 0 || t >= 128) return;
  const int H = 512 << l;
  const int oldS = (u + 1) & 1;
  const int grp = (l == 0) ? tile : ((l == 1) ? 8 + tile : 24 + tile);

  f32x4 acc[4][2] = {};
  if (l == 0) {
    if (kb == 0)
      gemm_run(p.xb + (size_t)t * 512, (size_t)128 * 512, p.wihzr0, 512,
               tile * 128, 0, As, Bs, acc);
    else
      gemm_run(p.hb[0][oldS], 512, p.whhzr[0], 512, tile * 128, 0, As, Bs,
               acc);
  } else if (l == 1) {
    gemm_run(p.hb[1][oldS], 1024, p.whhzr[1], 1024, tile * 128, kb * 512, As,
             Bs, acc);
  } else {
    gemm_run(p.hb[2][oldS], 2048, p.whhzr[2], 2048, tile * 128, kb * 512, As,
             Bs, acc);
  }

  float* pb0 = p.pzr + (size_t)grp * 4 * 16384;
  store_partial(pb0 + kb * 16384, acc);
  arrive_wait(p.czr + grp, G);

  // epilogue: this block's disjoint column share [kb*W, (kb+1)*W)
  const int W = 128 / G;
  const int row = tid >> 2;
  const int c0 = kb * W + (tid & 3) * (W / 4);
  const float* hfo = p.hf[l][oldS];
  const float* gil = (l == 0) ? (const float*)0 : p.gi[l][t & 1];
  for (int j = 0; j < W / 4; j += 4) {
    const int colL = c0 + j;
    f32x4 s = {};
    for (int k = 0; k < G; ++k)
      s += *(const f32x4*)(pb0 + (size_t)k * 16384 + row * 128 + colL);
#pragma unroll
    for (int e = 0; e < 4; ++e) {
      const int colg = tile * 128 + colL + e;
      float v = s[e] + p.bias[l][colg];
      if (l) v += gil[(size_t)row * 3 * H + colg];
      float sg = sigmoidf_(v);
      if (colg < H)
        p.zb[l][(size_t)row * H + colg] = sg;
      else {
        const int jj = colg - H;
        p.rh[l][(size_t)row * H + jj] = f2b(sg * hfo[(size_t)row * H + jj]);
      }
    }
  }
}

// ---- n: n-gate GEMMs + h update + out accum, plus gi projections. 208 ----
__global__ __launch_bounds__(512) void diag_n(DiagP p, int u) {
  __shared__ unsigned short As[2 * 16384], Bs[2 * 16384];
  const int blk = blockIdx.x, tid = threadIdx.x;
  if (blk == 0 && tid < 128) p.czr[tid] = 0;  // reset for next zr launch
  const int oldS = (u + 1) & 1, newS = u & 1;
  const int wave = tid >> 6, lane = tid & 63;
  const int wr = wave >> 2, wc = wave & 3, quad = lane >> 4, l16 = lane & 15;

  if (blk < 88) {
    int l, tile, kb, G;
    if (blk < 8) {
      l = 0; tile = blk >> 1; kb = blk & 1; G = 2;
    } else if (blk < 24) {
      l = 1; tile = (blk - 8) >> 1; kb = (blk - 8) & 1; G = 2;
    } else {
      l = 2; tile = (blk - 24) >> 2; kb = (blk - 24) & 3; G = 4;
    }
    const int t = u - 2 * l;
    if (t < 0 || t >= 128) return;
    const int H = 512 << l;
    const int outoff = (l == 0) ? 0 : ((l == 1) ? 512 : 1536);
    const int grp = (l == 0) ? tile : ((l == 1) ? 4 + tile : 12 + tile);

    f32x4 acc[4][2] = {};
    if (l == 0) {
      if (kb == 0)
        gemm_run(p.xb + (size_t)t * 512, (size_t)128 * 512, p.wihn0, 512,
                 tile * 128, 0, As, Bs, acc);
      else
        gemm_run(p.rh[0], 512, p.whhn[0], 512, tile * 128, 0, As, Bs, acc);
    } else if (l == 1) {
      gemm_run(p.rh[1], 1024, p.whhn[1], 1024, tile * 128, kb * 512, As, Bs,
               acc);
    } else {
      gemm_run(p.rh[2], 2048, p.whhn[2], 2048, tile * 128, kb * 512, As, Bs,
               acc);
    }

    float* pb0 = p.pn + (size_t)grp * 4 * 16384;
    store_partial(pb0 + kb * 16384, acc);
    arrive_wait(p.cn + grp, G);

    const int W = 128 / G;
    const int row = tid >> 2;
    const int c0 = kb * W + (tid & 3) * (W / 4);
    const float* hfo = p.hf[l][oldS];
    float* hfn = p.hf[l][newS];
    unsigned short* hbn = p.hb[l][newS];
    const float* gil =
        (l == 0) ? (const float*)0 : (p.gi[l][t & 1] + 2 * H);  // n chunk
    const float mrow = p.mask[row * 128 + t];
    for (int j = 0; j < W / 4; j += 4) {
      const int colL = c0 + j;
      f32x4 s = {};
      for (int k = 0; k < G; ++k)
        s += *(const f32x4*)(pb0 + (size_t)k * 16384 + row * 128 + colL);
#pragma unroll
      for (int e = 0; e < 4; ++e) {
        const int colg = tile * 128 + colL + e;
        float v = s[e] + p.bias[l][2 * H + colg];
        if (l) v += gil[(size_t)row * 3 * H + colg];
        float nv = tanhf_(v);
        size_t idx = (size_t)row * H + colg;
        float z = p.zb[l][idx];
        float hn = (1.0f - z) * nv + z * hfo[idx];
        hfn[idx] = hn;
        hbn[idx] = f2b(hn);
        p.out[(size_t)row * 3584 + outoff + colg] += mrow * hn;
      }
    }
  } else if (blk < 112) {
    // ---- gi1 (G=1): gi(1,tg) = h0(tg) @ WihF[1]^T, raw sums ----
    const int tile = blk - 88, tg = u - 1;
    if (tg < 0 || tg >= 128) return;
    f32x4 acc[4][2] = {};
    gemm_run(p.hb[0][oldS], 512, p.wihF[1], 512, tile * 128, 0, As, Bs, acc);
    float* gd = p.gi[1][tg & 1];
#pragma unroll
    for (int mi = 0; mi < 4; ++mi)
#pragma unroll
      for (int ni = 0; ni < 2; ++ni)
#pragma unroll
        for (int rr = 0; rr < 4; ++rr) {
          int row = wr * 64 + mi * 16 + quad * 4 + rr;
          int colg = tile * 128 + wc * 32 + ni * 16 + l16;
          gd[(size_t)row * 3072 + colg] = acc[mi][ni][rr];
        }
  } else {
    // ---- gi2 (G=2): gi(2,tg) = h1(tg) @ WihF[2]^T, raw sums ----
    const int idx = blk - 112, tile = idx >> 1, kb = idx & 1, tg = u - 3;
    if (tg < 0 || tg >= 128) return;
    const int grp = 28 + tile;
    f32x4 acc[4][2] = {};
    gemm_run(p.hb[1][oldS], 1024, p.wihF[2], 1024, tile * 128, kb * 512, As,
             Bs, acc);
    float* pb0 = p.pn + (size_t)grp * 4 * 16384;
    store_partial(pb0 + kb * 16384, acc);
    arrive_wait(p.cn + grp, 2);
    float* gd = p.gi[2][tg & 1];
    const int row = tid >> 2;
    const int c0 = kb * 64 + (tid & 3) * 16;
    for (int j = 0; j < 16; j += 4) {
      const int colL = c0 + j;
      f32x4 s = {};
      s += *(const f32x4*)(pb0 + (size_t)0 * 16384 + row * 128 + colL);
      s += *(const f32x4*)(pb0 + (size_t)1 * 16384 + row * 128 + colL);
#pragma unroll
      for (int e = 0; e < 4; ++e)
        gd[(size_t)row * 6144 + tile * 128 + colL + e] = s[e];
    }
  }
}

__global__ void cast_kernel(const float* __restrict__ src,
                            unsigned short* __restrict__ dst, int n) {
  int i = blockIdx.x * 256 + threadIdx.x;
  if (i < n) dst[i] = f2b(src[i]);
}

extern "C" void kernel_launch(void* const* d_in, const int* in_sizes, int n_in,
                              void* d_out, int out_size, void* d_ws,
                              size_t ws_size, hipStream_t stream) {
  const int B = 128, T = 128, I = 512;
  const int Hs[3] = {512, 1024, 2048};

  const float* x = (const float*)d_in[0];
  const float* mask = (const float*)d_in[1];
  const float* Wih[3] = {(const float*)d_in[2], (const float*)d_in[5],
                         (const float*)d_in[8]};
  const float* Whh[3] = {(const float*)d_in[3], (const float*)d_in[6],
                         (const float*)d_in[9]};
  const float* bias[3] = {(const float*)d_in[4], (const float*)d_in[7],
                          (const float*)d_in[10]};

  char* ws = (char*)d_ws;
  size_t off = 0;
  auto alloc = [&](size_t bytes) -> void* {
    void* p = ws + off;
    off = (off + bytes + 255) & ~(size_t)255;
    return p;
  };

  unsigned short* xb = (unsigned short*)alloc((size_t)B * T * I * 2);
  unsigned short *wihb[3], *whhb[3];
  for (int l = 0; l < 3; ++l) {
    int inl = (l == 0) ? I : Hs[l - 1];
    wihb[l] = (unsigned short*)alloc((size_t)3 * Hs[l] * inl * 2);
    whhb[l] = (unsigned short*)alloc((size_t)3 * Hs[l] * Hs[l] * 2);
  }
  size_t hstart = off;
  DiagP p;
  for (int l = 0; l < 3; ++l)
    for (int sl = 0; sl < 2; ++sl)
      p.hf[l][sl] = (float*)alloc((size_t)B * Hs[l] * 4);
  for (int l = 0; l < 3; ++l)
    for (int sl = 0; sl < 2; ++sl)
      p.hb[l][sl] = (unsigned short*)alloc((size_t)B * Hs[l] * 2);
  size_t hend = off;
  for (int l = 0; l < 3; ++l) p.zb[l] = (float*)alloc((size_t)B * Hs[l] * 4);
  for (int l = 0; l < 3; ++l)
    p.rh[l] = (unsigned short*)alloc((size_t)B * Hs[l] * 2);
  p.gi[0][0] = p.gi[0][1] = (float*)0;
  for (int l = 1; l < 3; ++l)
    for (int sl = 0; sl < 2; ++sl)
      p.gi[l][sl] = (float*)alloc((size_t)B * 3 * Hs[l] * 4);
  p.pzr = (float*)alloc((size_t)56 * 4 * 16384 * 4);
  p.pn = (float*)alloc((size_t)76 * 4 * 16384 * 4);
  p.czr = (int*)alloc(512);
  p.cn = (int*)alloc(512);
  (void)ws_size;

  p.xb = xb;
  p.wihzr0 = wihb[0];
  p.wihn0 = wihb[0] + (size_t)2 * Hs[0] * I;
  for (int l = 0; l < 3; ++l) {
    p.wihF[l] = wihb[l];
    p.whhzr[l] = whhb[l];
    p.whhn[l] = whhb[l] + (size_t)2 * Hs[l] * Hs[l];
    p.bias[l] = bias[l];
  }
  p.mask = mask;
  p.out = (float*)d_out;

  auto cast = [&](const float* s, unsigned short* d, int n) {
    cast_kernel<<<(n + 255) / 256, 256, 0, stream>>>(s, d, n);
  };
  cast(x, xb, B * T * I);
  for (int l = 0; l < 3; ++l) {
    int inl = (l == 0) ? I : Hs[l - 1];
    cast(Wih[l], wihb[l], 3 * Hs[l] * inl);
    cast(Whh[l], whhb[l], 3 * Hs[l] * Hs[l]);
  }
  hipMemsetAsync(ws + hstart, 0, hend - hstart, stream);
  hipMemsetAsync(p.czr, 0, 512, stream);
  hipMemsetAsync(p.cn, 0, 512, stream);
  hipMemsetAsync(d_out, 0, (size_t)out_size * 4, stream);

  // ---- diagonal scan: tick u covers layer l at t = u - 2l ----
  for (int u = 0; u < 132; ++u) {
    diag_zr<<<176, 512, 0, stream>>>(p, u);
    diag_n<<<208, 512, 0, stream>>>(p, u);
  }
}

// Round 3
// 9260.346 us; speedup vs baseline: 2.3226x; 2.3226x over previous
//
#include <hip/hip_runtime.h>
#include <hip/hip_bf16.h>

// ---------------------------------------------------------------------------
// 3-layer original-paper GRU, B=128, T=128, I=512, H={512,1024,2048}.
// Round 8: R6 schedule (proven 7817us) + deep-pipelined GEMM core.
//  - R7's split-K spin barrier regressed 2.75x (coherence storms): REVERTED.
//  - New engine: BK=64 phases, 4-slot LDS ring (4x16KB A + 4x8KB B = 96KB),
//    3-deep prefetch with counted s_waitcnt vmcnt(6) -- loads stay in flight
//    across barriers (T3+T4), one s_barrier per phase, s_setprio around MFMA.
//  - Same diagonal schedule as R6: tick u = layer l at t=u-2l, gi decoupled,
//    h f32+bf16 double-buffered by tick parity. Epilogues byte-identical.
// ---------------------------------------------------------------------------

typedef __attribute__((ext_vector_type(8))) short s16x8;
typedef __attribute__((ext_vector_type(4))) float f32x4;

#define LLDS16(g, s)                                                          \
  __builtin_amdgcn_global_load_lds(                                           \
      (const __attribute__((address_space(1))) void*)(g),                     \
      (__attribute__((address_space(3))) void*)(s), 16, 0, 0)

__device__ __forceinline__ unsigned short f2b(float f) {
  unsigned int u = __float_as_uint(f);
  unsigned int r = (u + 0x7FFFu + ((u >> 16) & 1u)) >> 16;
  return (unsigned short)r;
}
__device__ __forceinline__ float sigmoidf_(float x) {
  return 1.0f / (1.0f + __expf(-x));
}
__device__ __forceinline__ float tanhf_(float x) {
  x = fminf(fmaxf(x, -15.0f), 15.0f);
  float e = __expf(-2.0f * x);
  return (1.0f - e) / (1.0f + e);
}

struct DiagP {
  const unsigned short* xb;            // [B,T,I] bf16
  const unsigned short* wihzr0;        // [2*512, 512]
  const unsigned short* wihn0;         // [512, 512]
  const unsigned short* wihF[3];       // full [3H, inl] (l=1,2 used)
  const unsigned short* whhzr[3];      // [2H, H]
  const unsigned short* whhn[3];       // [H, H]
  const float* bias[3];                // [3H]
  float* hf[3][2];                     // f32 h, 2 slots (tick parity)
  unsigned short* hb[3][2];            // bf16 h, 2 slots
  float* zb[3];                        // [B,H] f32
  unsigned short* rh[3];               // [B,H] bf16
  float* gi[3][2];                     // [B,3H] f32, 2 slots (t parity)
  const float* mask;                   // [B,T]
  float* out;                          // [B,3584]
};

// ---- staging, BK=64: A tile 128x64 (16KB), B tile 64x64 (8KB) -------------
// LDS row r at r*128B, 8 slots of 16B; slot holds src col-group slot^(r&7).
__device__ __forceinline__ void stageA64(const unsigned short* __restrict__ g,
                                         size_t ld, int k0,
                                         unsigned short* lds) {
  const int tid = threadIdx.x;
  const int wave = tid >> 6, lane = tid & 63;
#pragma unroll
  for (int j = 0; j < 2; ++j) {
    int s = wave * 2 + j;             // 0..15, 1KB segments (8 rows each)
    int r = s * 8 + (lane >> 3);      // 0..127
    int cg = (lane & 7) ^ (r & 7);
    LLDS16(g + (size_t)r * ld + k0 + cg * 8, lds + s * 512);
  }
}
__device__ __forceinline__ void stageB64(const unsigned short* __restrict__ g,
                                         size_t ld, int rowbase, int k0,
                                         unsigned short* lds) {
  const int tid = threadIdx.x;
  const int wave = tid >> 6, lane = tid & 63;
  int r = wave * 8 + (lane >> 3);     // 0..63
  int cg = (lane & 7) ^ (r & 7);
  LLDS16(g + (size_t)(rowbase + r) * ld + k0 + cg * 8, lds + wave * 512);
}

// ---- one BK=64 phase: wave (wr=wave>>1, wcp=wave&1) computes rows
// wr*32+[0,32), cols wcp*32+[0,32): 8 ds_read_b128 + 8 MFMA per phase.
__device__ __forceinline__ void cchunk64(const unsigned short* Ab,
                                         const unsigned short* Bb,
                                         f32x4 acc[2][2]) {
  const int tid = threadIdx.x;
  const int wave = tid >> 6, lane = tid & 63;
  const int wr = wave >> 1, wcp = wave & 1, quad = lane >> 4, l16 = lane & 15;
#pragma unroll
  for (int ks = 0; ks < 2; ++ks) {
    int kg = ks * 4 + quad;           // 0..7
    s16x8 bv[2], av[2];
#pragma unroll
    for (int ni = 0; ni < 2; ++ni) {
      int br = wcp * 32 + ni * 16 + l16;
      bv[ni] = *(const s16x8*)(Bb + (size_t)br * 64 + ((kg ^ (br & 7)) * 8));
    }
#pragma unroll
    for (int mi = 0; mi < 2; ++mi) {
      int ar = wr * 32 + mi * 16 + l16;
      av[mi] = *(const s16x8*)(Ab + (size_t)ar * 64 + ((kg ^ (ar & 7)) * 8));
    }
#pragma unroll
    for (int mi = 0; mi < 2; ++mi)
#pragma unroll
      for (int ni = 0; ni < 2; ++ni)
        acc[mi][ni] = __builtin_amdgcn_mfma_f32_16x16x32_bf16(
            av[mi], bv[ni], acc[mi][ni], 0, 0, 0);
  }
}

// acc += A1@B1^T (p1 phases of 64) + A2@B2^T (p2 phases); B rows at rowbase.
// 3-deep prefetch, counted vmcnt, one barrier per phase. total >= 3 required.
__device__ __forceinline__ void gemm_diag(
    const unsigned short* __restrict__ A1, size_t ldA1, int p1,
    const unsigned short* __restrict__ A2, size_t ldA2, int p2,
    const unsigned short* __restrict__ B1, size_t ldB1,
    const unsigned short* __restrict__ B2, size_t ldB2, int rowbase,
    unsigned short* As, unsigned short* Bs, f32x4 acc[2][2]) {
  const int total = p1 + p2;
  auto issue = [&](int q) {
    unsigned short* a = As + (q & 3) * 8192;
    unsigned short* b = Bs + (q & 3) * 4096;
    if (q < p1) {
      stageA64(A1, ldA1, q << 6, a);
      stageB64(B1, ldB1, rowbase, q << 6, b);
    } else {
      int k0 = (q - p1) << 6;
      stageA64(A2, ldA2, k0, a);
      stageB64(B2, ldB2, rowbase, k0, b);
    }
  };
  issue(0);
  issue(1);
  issue(2);
#pragma unroll 1
  for (int p = 0; p < total; ++p) {
    const int rem = total - 1 - p;
    // Wait: phase p's 3 loads done (oldest); up to 6 newer stay in flight.
    // lgkmcnt(0): my ds_reads of phase p-1 retired (WAR vs issue below).
    if (rem >= 2)
      asm volatile("s_waitcnt vmcnt(6) lgkmcnt(0)" ::: "memory");
    else if (rem == 1)
      asm volatile("s_waitcnt vmcnt(3) lgkmcnt(0)" ::: "memory");
    else
      asm volatile("s_waitcnt vmcnt(0) lgkmcnt(0)" ::: "memory");
    __builtin_amdgcn_s_barrier();
    asm volatile("" ::: "memory");  // fence: no ds_read hoists above barrier
    // Safe to overwrite slot (p+3)&3 == (p-1)&3: all waves passed the
    // barrier, so all finished reading phase p-1.
    if (p + 3 < total) issue(p + 3);
    __builtin_amdgcn_s_setprio(1);
    cchunk64(As + (p & 3) * 8192, Bs + (p & 3) * 4096, acc);
    __builtin_amdgcn_s_setprio(0);
  }
}

// ---- zr: hidden-zr gates for tick u (L0 fused with x-proj). 112 blocks. ----
__global__ __launch_bounds__(512) void diag_zr(DiagP p, int u) {
  __shared__ unsigned short As[4 * 8192], Bs[4 * 4096];
  const int blk = blockIdx.x;
  const int l = (blk < 16) ? 0 : ((blk < 48) ? 1 : 2);
  const int nt = blk - ((l == 0) ? 0 : ((l == 1) ? 16 : 48));
  const int t = u - 2 * l;
  if (t < 0 || t >= 128) return;
  const int H = 512 << l;
  const int oldS = (u + 1) & 1;

  f32x4 acc[2][2] = {};
  if (l == 0) {
    gemm_diag(p.xb + (size_t)t * 512, (size_t)128 * 512, 8, p.hb[0][oldS], 512,
              8, p.wihzr0, 512, p.whhzr[0], 512, nt * 64, As, Bs, acc);
  } else {
    gemm_diag(p.hb[l][oldS], (size_t)H, H >> 6, (const unsigned short*)0, 0, 0,
              p.whhzr[l], (size_t)H, (const unsigned short*)0, 0, nt * 64, As,
              Bs, acc);
  }

  const int tid = threadIdx.x, wave = tid >> 6, lane = tid & 63;
  const int wr = wave >> 1, wcp = wave & 1, quad = lane >> 4, l16 = lane & 15;
  const float* hfo = p.hf[l][oldS];
  const float* gil = (l == 0) ? (const float*)0 : p.gi[l][t & 1];
#pragma unroll
  for (int ni = 0; ni < 2; ++ni) {
    const int colg = nt * 64 + wcp * 32 + ni * 16 + l16;
    const float bv = p.bias[l][colg];
    const bool isz = colg < H;  // uniform per block (64 | H)
    const int j = isz ? colg : colg - H;
#pragma unroll
    for (int mi = 0; mi < 2; ++mi)
#pragma unroll
      for (int r = 0; r < 4; ++r) {
        const int row = wr * 32 + mi * 16 + quad * 4 + r;
        float v = acc[mi][ni][r] + bv;
        if (l) v += gil[(size_t)row * 3 * H + colg];
        float s = sigmoidf_(v);
        if (isz)
          p.zb[l][(size_t)row * H + j] = s;
        else
          p.rh[l][(size_t)row * H + j] = f2b(s * hfo[(size_t)row * H + j]);
      }
  }
}

// ---- n: n gate + h update + masked out accum, PLUS next ticks' input
// projections gi(l,t) for l=1,2. 200 blocks. ----
__global__ __launch_bounds__(512) void diag_n(DiagP p, int u) {
  __shared__ unsigned short As[4 * 8192], Bs[4 * 4096];
  const int blk = blockIdx.x;
  const int tid = threadIdx.x, wave = tid >> 6, lane = tid & 63;
  const int wr = wave >> 1, wcp = wave & 1, quad = lane >> 4, l16 = lane & 15;
  const int oldS = (u + 1) & 1, newS = u & 1;

  if (blk < 56) {
    // ---- n-gate blocks ----
    const int l = (blk < 8) ? 0 : ((blk < 24) ? 1 : 2);
    const int nt = blk - ((l == 0) ? 0 : ((l == 1) ? 8 : 24));
    const int t = u - 2 * l;
    if (t < 0 || t >= 128) return;
    const int H = 512 << l;
    const int outoff = (l == 0) ? 0 : ((l == 1) ? 512 : 1536);

    f32x4 acc[2][2] = {};
    if (l == 0) {
      gemm_diag(p.xb + (size_t)t * 512, (size_t)128 * 512, 8, p.rh[0], 512, 8,
                p.wihn0, 512, p.whhn[0], 512, nt * 64, As, Bs, acc);
    } else {
      gemm_diag(p.rh[l], (size_t)H, H >> 6, (const unsigned short*)0, 0, 0,
                p.whhn[l], (size_t)H, (const unsigned short*)0, 0, nt * 64, As,
                Bs, acc);
    }

    const float* hfo = p.hf[l][oldS];
    float* hfn = p.hf[l][newS];
    unsigned short* hbn = p.hb[l][newS];
    const float* gil =
        (l == 0) ? (const float*)0 : (p.gi[l][t & 1] + 2 * H);  // n chunk
#pragma unroll
    for (int ni = 0; ni < 2; ++ni) {
      const int colg = nt * 64 + wcp * 32 + ni * 16 + l16;
      const float bv = p.bias[l][2 * H + colg];
#pragma unroll
      for (int mi = 0; mi < 2; ++mi)
#pragma unroll
        for (int r = 0; r < 4; ++r) {
          const int row = wr * 32 + mi * 16 + quad * 4 + r;
          float v = acc[mi][ni][r] + bv;
          if (l) v += gil[(size_t)row * 3 * H + colg];
          float nv = tanhf_(v);
          size_t idx = (size_t)row * H + colg;
          float z = p.zb[l][idx];
          float hn = (1.0f - z) * nv + z * hfo[idx];
          hfn[idx] = hn;
          hbn[idx] = f2b(hn);
          p.out[(size_t)row * 3584 + outoff + colg] +=
              p.mask[row * 128 + t] * hn;
        }
    }
  } else if (blk < 104) {
    // ---- gi1: gi(1,tg) = h0(tg) @ WihF[1]^T (raw, no bias) ----
    const int g = blk - 56;  // 0..47, col tiles of 3*1024
    const int tg = u - 1;    // consumed by zr(1,tg) at tick tg+2 = u+1
    if (tg < 0 || tg >= 128) return;
    f32x4 acc[2][2] = {};
    gemm_diag(p.hb[0][oldS], 512, 8, (const unsigned short*)0, 0, 0,
              p.wihF[1], 512, (const unsigned short*)0, 0, g * 64, As, Bs,
              acc);
    float* gd = p.gi[1][tg & 1];
#pragma unroll
    for (int ni = 0; ni < 2; ++ni)
#pragma unroll
      for (int mi = 0; mi < 2; ++mi)
#pragma unroll
        for (int rr = 0; rr < 4; ++rr) {
          int row = wr * 32 + mi * 16 + quad * 4 + rr;
          int colg = g * 64 + wcp * 32 + ni * 16 + l16;
          gd[(size_t)row * 3072 + colg] = acc[mi][ni][rr];
        }
  } else {
    // ---- gi2: gi(2,tg) = h1(tg) @ WihF[2]^T (raw, no bias) ----
    const int g = blk - 104;  // 0..95, col tiles of 3*2048
    const int tg = u - 3;     // consumed by zr(2,tg) at tick tg+4 = u+1
    if (tg < 0 || tg >= 128) return;
    f32x4 acc[2][2] = {};
    gemm_diag(p.hb[1][oldS], 1024, 16, (const unsigned short*)0, 0, 0,
              p.wihF[2], 1024, (const unsigned short*)0, 0, g * 64, As, Bs,
              acc);
    float* gd = p.gi[2][tg & 1];
#pragma unroll
    for (int ni = 0; ni < 2; ++ni)
#pragma unroll
      for (int mi = 0; mi < 2; ++mi)
#pragma unroll
        for (int rr = 0; rr < 4; ++rr) {
          int row = wr * 32 + mi * 16 + quad * 4 + rr;
          int colg = g * 64 + wcp * 32 + ni * 16 + l16;
          gd[(size_t)row * 6144 + colg] = acc[mi][ni][rr];
        }
  }
}

__global__ void cast_kernel(const float* __restrict__ src,
                            unsigned short* __restrict__ dst, int n) {
  int i = blockIdx.x * 256 + threadIdx.x;
  if (i < n) dst[i] = f2b(src[i]);
}

extern "C" void kernel_launch(void* const* d_in, const int* in_sizes, int n_in,
                              void* d_out, int out_size, void* d_ws,
                              size_t ws_size, hipStream_t stream) {
  const int B = 128, T = 128, I = 512;
  const int Hs[3] = {512, 1024, 2048};

  const float* x = (const float*)d_in[0];
  const float* mask = (const float*)d_in[1];
  const float* Wih[3] = {(const float*)d_in[2], (const float*)d_in[5],
                         (const float*)d_in[8]};
  const float* Whh[3] = {(const float*)d_in[3], (const float*)d_in[6],
                         (const float*)d_in[9]};
  const float* bias[3] = {(const float*)d_in[4], (const float*)d_in[7],
                          (const float*)d_in[10]};

  char* ws = (char*)d_ws;
  size_t off = 0;
  auto alloc = [&](size_t bytes) -> void* {
    void* p = ws + off;
    off = (off + bytes + 255) & ~(size_t)255;
    return p;
  };

  unsigned short* xb = (unsigned short*)alloc((size_t)B * T * I * 2);
  unsigned short *wihb[3], *whhb[3];
  for (int l = 0; l < 3; ++l) {
    int inl = (l == 0) ? I : Hs[l - 1];
    wihb[l] = (unsigned short*)alloc((size_t)3 * Hs[l] * inl * 2);
    whhb[l] = (unsigned short*)alloc((size_t)3 * Hs[l] * Hs[l] * 2);
  }
  size_t hstart = off;
  DiagP p;
  for (int l = 0; l < 3; ++l)
    for (int sl = 0; sl < 2; ++sl)
      p.hf[l][sl] = (float*)alloc((size_t)B * Hs[l] * 4);
  for (int l = 0; l < 3; ++l)
    for (int sl = 0; sl < 2; ++sl)
      p.hb[l][sl] = (unsigned short*)alloc((size_t)B * Hs[l] * 2);
  size_t hend = off;
  for (int l = 0; l < 3; ++l) p.zb[l] = (float*)alloc((size_t)B * Hs[l] * 4);
  for (int l = 0; l < 3; ++l)
    p.rh[l] = (unsigned short*)alloc((size_t)B * Hs[l] * 2);
  p.gi[0][0] = p.gi[0][1] = (float*)0;
  for (int l = 1; l < 3; ++l)
    for (int sl = 0; sl < 2; ++sl)
      p.gi[l][sl] = (float*)alloc((size_t)B * 3 * Hs[l] * 4);
  (void)ws_size;

  p.xb = xb;
  p.wihzr0 = wihb[0];
  p.wihn0 = wihb[0] + (size_t)2 * Hs[0] * I;
  for (int l = 0; l < 3; ++l) {
    p.wihF[l] = wihb[l];
    p.whhzr[l] = whhb[l];
    p.whhn[l] = whhb[l] + (size_t)2 * Hs[l] * Hs[l];
    p.bias[l] = bias[l];
  }
  p.mask = mask;
  p.out = (float*)d_out;

  auto cast = [&](const float* s, unsigned short* d, int n) {
    cast_kernel<<<(n + 255) / 256, 256, 0, stream>>>(s, d, n);
  };
  cast(x, xb, B * T * I);
  for (int l = 0; l < 3; ++l) {
    int inl = (l == 0) ? I : Hs[l - 1];
    cast(Wih[l], wihb[l], 3 * Hs[l] * inl);
    cast(Whh[l], whhb[l], 3 * Hs[l] * Hs[l]);
  }
  hipMemsetAsync(ws + hstart, 0, hend - hstart, stream);
  hipMemsetAsync(d_out, 0, (size_t)out_size * 4, stream);

  // ---- diagonal scan: tick u covers layer l at t = u - 2l ----
  // zr(2,127) and n(2,127) land at u = 131.
  for (int u = 0; u < 132; ++u) {
    diag_zr<<<112, 512, 0, stream>>>(p, u);
    diag_n<<<200, 512, 0, stream>>>(p, u);
  }
}